// Round 1
// baseline (359.407 us; speedup 1.0000x reference)
//
#include <hip/hip_runtime.h>
#include <hip/hip_bf16.h>

// CTC forward-algorithm loss (ocropus-style 2-term DP).
// S=1024 steps, T=2L+1=257 states, N=32 batch, C=128 classes.
// Plan:
//   k1: precompute m[s][n][t] = log(p[s,n,cls_t]) - log(sum_c p[s,n,c])   (parallel)
//   k2: serial DP per batch (1 wave/block, 5 states/lane, 8-deep m prefetch)
//   k3: sum 32 losses -> d_out[0] = sum/32

#define S_LEN 1024
#define N_B   32
#define C_CLS 128
#define T_ST  257
#define TP    260      // m row stride (floats)
#define VS    320      // v-state row stride (floats), 5*64 lanes
#define SKIPV (-5.0f)
#define LOV   (1e-5f)

__device__ __forceinline__ float log_add2(float x, float y) {
    float d = x - y;
    // clip in reference is inert inside the |d|<=10 branch
    float s = __logf(__expf(d) + 1.0f) + y;
    return (fabsf(d) > 10.0f) ? fmaxf(x, y) : s;
}

// ---- kernel 1: per-(s,n) row -> m row (TP floats) --------------------------
__global__ void ctc_pre_kernel(const float* __restrict__ inp,
                               const int* __restrict__ lab,
                               float* __restrict__ m,
                               int chunk_start, int ch) {
    __shared__ float lp[4][C_CLS];
    const int wid  = threadIdx.x >> 6;
    const int lane = threadIdx.x & 63;
    const int r = blockIdx.x * 4 + wid;
    if (r >= ch * N_B) return;
    const int s_local = r >> 5;            // / N_B
    const int n = r & 31;                  // % N_B
    const int s = chunk_start + s_local;

    const float* row = inp + ((size_t)s * N_B + n) * C_CLS;
    float2 x = *(const float2*)(row + 2 * lane);
    float p0 = fmaxf(LOV, x.x);
    float p1 = fmaxf(LOV, x.y);
    float sum = p0 + p1;
    #pragma unroll
    for (int off = 32; off; off >>= 1) sum += __shfl_xor(sum, off);
    float logS = __logf(sum);
    lp[wid][2 * lane]     = __logf(p0) - logS;
    lp[wid][2 * lane + 1] = __logf(p1) - logS;
    // single-wave LDS slice: wave-ordered DS ops, no barrier needed

    float* mrow = m + ((size_t)s_local * N_B + n) * TP;
    #pragma unroll
    for (int q = 0; q < 4; ++q) {
        int t = q * 64 + lane;                       // 0..255
        int cls = (t & 1) ? lab[((t - 1) >> 1) * N_B + n] : 0;
        mrow[t] = lp[wid][cls];
    }
    if (lane == 0) mrow[256] = lp[wid][0];           // t=256 even -> blank
    if (lane >= 1 && lane <= 3) mrow[256 + lane] = 0.0f;  // pad 257..259
}

// ---- kernel 2: serial DP, one wave per batch element -----------------------
__global__ void __launch_bounds__(64)
ctc_dp_kernel(const float* __restrict__ m,
              float* __restrict__ vst,
              float* __restrict__ losses,
              int chunk_start, int ch) {
    const int n = blockIdx.x;
    const int lane = threadIdx.x;
    const int t0 = 5 * lane;               // lane owns states t0..t0+4 (t<257 valid)

    float v0, v1, v2, v3, v4;
    float* vrow = vst + (size_t)n * VS;
    if (chunk_start == 0) {
        v0 = SKIPV * (float)(t0 + 0);
        v1 = SKIPV * (float)(t0 + 1);
        v2 = SKIPV * (float)(t0 + 2);
        v3 = SKIPV * (float)(t0 + 3);
        v4 = SKIPV * (float)(t0 + 4);
    } else {
        v0 = vrow[t0 + 0]; v1 = vrow[t0 + 1]; v2 = vrow[t0 + 2];
        v3 = vrow[t0 + 3]; v4 = vrow[t0 + 4];
    }

    const float* mb_base = m + (size_t)n * TP + t0;
    const size_t rstride = (size_t)N_B * TP;

    float mb[8][5];                        // compile-time indexed only
    #pragma unroll
    for (int k = 0; k < 8; ++k) {          // ch is always a multiple of 8
        const float* rr = mb_base + (size_t)k * rstride;
        #pragma unroll
        for (int j = 0; j < 5; ++j) mb[k][j] = rr[j];
    }

    for (int i0 = 0; i0 < ch; i0 += 8) {
        #pragma unroll
        for (int k = 0; k < 8; ++k) {
            const int i = i0 + k;
            float prev = __shfl_up(v4, 1);
            if (lane == 0) prev = SKIPV * (float)(chunk_start + i);
            float a0 = mb[k][0] + log_add2(v0, prev);
            float a1 = mb[k][1] + log_add2(v1, v0);
            float a2 = mb[k][2] + log_add2(v2, v1);
            float a3 = mb[k][3] + log_add2(v3, v2);
            float a4 = mb[k][4] + log_add2(v4, v3);
            v0 = a0; v1 = a1; v2 = a2; v3 = a3; v4 = a4;
            int ip = i + 8; if (ip > ch - 1) ip = ch - 1;   // clamp prefetch
            const float* rr = mb_base + (size_t)ip * rstride;
            #pragma unroll
            for (int j = 0; j < 5; ++j) mb[k][j] = rr[j];
        }
    }

    if (chunk_start + ch < S_LEN) {
        vrow[t0 + 0] = v0; vrow[t0 + 1] = v1; vrow[t0 + 2] = v2;
        vrow[t0 + 3] = v3; vrow[t0 + 4] = v4;
    } else if (lane == 51) {
        // lane 51: v0 = v[255], v1 = v[256]; loss = -log_add(v[256], v[255])
        losses[n] = -log_add2(v1, v0);
    }
}

// ---- kernel 3: reduce losses -> scalar -------------------------------------
__global__ void ctc_sum_kernel(const float* __restrict__ losses,
                               float* __restrict__ out) {
    const int lane = threadIdx.x;
    float x = (lane < N_B) ? losses[lane] : 0.0f;
    #pragma unroll
    for (int off = 32; off; off >>= 1) x += __shfl_xor(x, off);
    if (lane == 0) out[0] = x / (float)N_B;
}

extern "C" void kernel_launch(void* const* d_in, const int* in_sizes, int n_in,
                              void* d_out, int out_size, void* d_ws, size_t ws_size,
                              hipStream_t stream) {
    const float* inp = (const float*)d_in[0];   // (S, N, C) f32
    const int*   lab = (const int*)d_in[1];     // (L, N) int32
    float* out = (float*)d_out;

    char* ws = (char*)d_ws;
    const size_t V_OFF = 0;                                   // N*VS floats
    const size_t L_OFF = (size_t)N_B * VS * 4;                // 40960
    const size_t M_OFF = (L_OFF + N_B * 4 + 255) & ~(size_t)255;
    float* vst    = (float*)(ws + V_OFF);
    float* losses = (float*)(ws + L_OFF);
    float* mbuf   = (float*)(ws + M_OFF);

    // chunk length: multiple of 8 rows of (N_B*TP floats), leave 512B tail pad
    size_t usable = (ws_size > M_OFF + 4096) ? (ws_size - M_OFF - 512) : 0;
    int CH = (int)(usable / ((size_t)N_B * TP * 4));
    CH &= ~7;
    if (CH > S_LEN) CH = S_LEN;
    if (CH < 8) CH = 8;   // ws is expected to be far larger than 300 KB

    for (int cs = 0; cs < S_LEN; cs += CH) {
        int ch = S_LEN - cs; if (ch > CH) ch = CH;
        int rows = ch * N_B;
        int pre_blocks = (rows + 3) / 4;
        ctc_pre_kernel<<<pre_blocks, 256, 0, stream>>>(inp, lab, mbuf, cs, ch);
        ctc_dp_kernel<<<N_B, 64, 0, stream>>>(mbuf, vst, losses, cs, ch);
    }
    ctc_sum_kernel<<<1, 64, 0, stream>>>(losses, out);
}

// Round 2
// 264.449 us; speedup vs baseline: 1.3591x; 1.3591x over previous
//
#include <hip/hip_runtime.h>
#include <hip/hip_bf16.h>

// CTC forward loss. k1: q[s][n][t] = p[cls_t]/sum (prob domain, no logs).
// k2: serial DP per batch in LINEAR domain with per-lane log-offset `ref`
//     and per-step max rescale; rows staged via global_load_lds into a
//     17-slot LDS ring, 16 rows in flight, counted vmcnt waits.
// k3: sum losses -> scalar.

#define S_LEN 1024
#define N_B   32
#define C_CLS 128
#define TP    260      // q row stride in floats (1040 B, 16B-aligned)
#define TLDS  320      // LDS ring row stride (covers 64 lanes x 5 states)
#define RING  17
#define DEPTH 16
#define SKIPV (-5.0f)
#define LOV   (1e-5f)

__device__ __forceinline__ void dma16(const float* g, float* l) {
    __builtin_amdgcn_global_load_lds((const __attribute__((address_space(1))) void*)g,
                                     (__attribute__((address_space(3))) void*)l, 16, 0, 0);
}
__device__ __forceinline__ void dma4(const float* g, float* l) {
    __builtin_amdgcn_global_load_lds((const __attribute__((address_space(1))) void*)g,
                                     (__attribute__((address_space(3))) void*)l, 4, 0, 0);
}

// ---- kernel 1: per-(s,n) row -> q row (probabilities) ----------------------
__global__ void ctc_pre_kernel(const float* __restrict__ inp,
                               const int* __restrict__ lab,
                               float* __restrict__ m,
                               int chunk_start, int ch) {
    __shared__ float lp[4][C_CLS];
    const int wid  = threadIdx.x >> 6;
    const int lane = threadIdx.x & 63;
    const int r = blockIdx.x * 4 + wid;
    if (r >= ch * N_B) return;
    const int s_local = r >> 5;
    const int n = r & 31;
    const int s = chunk_start + s_local;

    const float* row = inp + ((size_t)s * N_B + n) * C_CLS;
    float2 x = *(const float2*)(row + 2 * lane);
    float p0 = fmaxf(LOV, x.x);
    float p1 = fmaxf(LOV, x.y);
    float sum = p0 + p1;
    #pragma unroll
    for (int off = 32; off; off >>= 1) sum += __shfl_xor(sum, off);
    float rinv = 1.0f / sum;
    lp[wid][2 * lane]     = p0 * rinv;
    lp[wid][2 * lane + 1] = p1 * rinv;
    // single-wave LDS slice: wave-ordered, no barrier needed

    float* mrow = m + ((size_t)s_local * N_B + n) * TP;
    #pragma unroll
    for (int q = 0; q < 4; ++q) {
        int t = q * 64 + lane;                       // 0..255
        int cls = (t & 1) ? lab[((t - 1) >> 1) * N_B + n] : 0;
        mrow[t] = lp[wid][cls];
    }
    if (lane == 0) mrow[256] = lp[wid][0];           // t=256 -> blank
    if (lane >= 1 && lane <= 3) mrow[256 + lane] = 0.0f;  // pad 257..259 = 0
}

// ---- kernel 2: serial DP, linear domain, LDS-ring staged -------------------
__global__ void __launch_bounds__(64)
ctc_dp_kernel(const float* __restrict__ q,
              float* __restrict__ vst,       // (N, 64, 6) u0..u4, ref
              float* __restrict__ losses,
              int chunk_start, int ch) {
    __shared__ float ring[RING][TLDS];
    const int n = blockIdx.x;
    const int lane = threadIdx.x;

    const size_t rstride = (size_t)N_B * TP;
    const float* qn = q + (size_t)n * TP;

    float u0, u1, u2, u3, u4, ref;
    if (chunk_start == 0) {
        ref = SKIPV * (float)(5 * lane);   // v[t0]; lane max (downhill init)
        u0 = 1.0f;
        u1 = 6.73794700e-03f;   // e^-5
        u2 = 4.53999298e-05f;   // e^-10
        u3 = 3.05902321e-07f;   // e^-15
        u4 = 2.06115362e-09f;   // e^-20
    } else {
        const float* vr = vst + ((size_t)n * 64 + lane) * 6;
        u0 = vr[0]; u1 = vr[1]; u2 = vr[2]; u3 = vr[3]; u4 = vr[4]; ref = vr[5];
    }

    // prologue: DMA rows 0..DEPTH-1 into slots 0..15
    for (int r = 0; r < DEPTH; ++r) {
        int rr = (r < ch) ? r : (ch - 1);
        const float* src = qn + (size_t)rr * rstride;
        dma16(src + 4 * lane, &ring[r][0]);          // floats 0..255
        dma4(src + 256 + lane, &ring[r][256]);       // floats 256..319
    }
    asm volatile("s_waitcnt vmcnt(30)" ::: "memory");   // row 0 landed
    __builtin_amdgcn_sched_barrier(0);
    float r0 = ring[0][5 * lane + 0], r1 = ring[0][5 * lane + 1],
          r2 = ring[0][5 * lane + 2], r3 = ring[0][5 * lane + 3],
          r4 = ring[0][5 * lane + 4];

    int fill_slot = DEPTH;   // slot for row 16
    int read_slot = 1;       // slot for row 1
    for (int i = 0; i < ch; ++i) {
        // refill: row i+16 into slot (i+16)%17 (== slot of row i-1, read-complete)
        int rf = i + DEPTH; if (rf >= ch) rf = ch - 1;
        const float* src = qn + (size_t)rf * rstride;
        dma16(src + 4 * lane, &ring[fill_slot][0]);
        dma4(src + 256 + lane, &ring[fill_slot][256]);
        // row i+1's 2 loads are among the 4 oldest of <=32 outstanding
        asm volatile("s_waitcnt vmcnt(28)" ::: "memory");
        __builtin_amdgcn_sched_barrier(0);
        const float* rrow = &ring[read_slot][5 * lane];
        float n0 = rrow[0], n1 = rrow[1], n2 = rrow[2], n3 = rrow[3], n4 = rrow[4];

        // boundary: prev = exp(v[t0-1] - ref) ; lane0 uses skip state
        float ref_s = __shfl_up(ref, 1);
        float u4_s  = __shfl_up(u4, 1);
        float d  = ref_s - ref;          // <= ~82 by DP invariant, fits f32 exp
        float us = u4_s;
        if (lane == 0) { d = SKIPV * (float)(chunk_start + i) - ref; us = 1.0f; }
        float prev = us * __expf(d);

        float w0 = r0 * (u0 + prev);
        float w1 = r1 * (u1 + u0);
        float w2 = r2 * (u2 + u1);
        float w3 = r3 * (u3 + u2);
        float w4 = r4 * (u4 + u3);
        float M = fmaxf(fmaxf(fmaxf(w0, w1), fmaxf(w2, w3)), w4);
        float rcpM; asm("v_rcp_f32 %0, %1" : "=v"(rcpM) : "v"(M));
        ref += __logf(M);
        u0 = w0 * rcpM; u1 = w1 * rcpM; u2 = w2 * rcpM;
        u3 = w3 * rcpM; u4 = w4 * rcpM;

        r0 = n0; r1 = n1; r2 = n2; r3 = n3; r4 = n4;
        fill_slot = (fill_slot == RING - 1) ? 0 : fill_slot + 1;
        read_slot = (read_slot == RING - 1) ? 0 : read_slot + 1;
    }

    if (chunk_start + ch < S_LEN) {
        float* vr = vst + ((size_t)n * 64 + lane) * 6;
        vr[0] = u0; vr[1] = u1; vr[2] = u2; vr[3] = u3; vr[4] = u4; vr[5] = ref;
    } else if (lane == 51) {
        // lane 51: u0 = state 255, u1 = state 256 (max(u0,u1)=1, never both 0)
        losses[n] = -(ref + __logf(u0 + u1));
    }
}

// ---- kernel 3: reduce losses -> scalar -------------------------------------
__global__ void ctc_sum_kernel(const float* __restrict__ losses,
                               float* __restrict__ out) {
    const int lane = threadIdx.x;
    float x = (lane < N_B) ? losses[lane] : 0.0f;
    #pragma unroll
    for (int off = 32; off; off >>= 1) x += __shfl_xor(x, off);
    if (lane == 0) out[0] = x / (float)N_B;
}

extern "C" void kernel_launch(void* const* d_in, const int* in_sizes, int n_in,
                              void* d_out, int out_size, void* d_ws, size_t ws_size,
                              hipStream_t stream) {
    const float* inp = (const float*)d_in[0];   // (S, N, C) f32
    const int*   lab = (const int*)d_in[1];     // (L, N) int
    float* out = (float*)d_out;

    char* ws = (char*)d_ws;
    const size_t V_BYTES = (size_t)N_B * 64 * 6 * 4;          // 49152
    const size_t L_OFF = V_BYTES;
    const size_t M_OFF = (L_OFF + N_B * 4 + 255) & ~(size_t)255;
    float* vst    = (float*)ws;
    float* losses = (float*)(ws + L_OFF);
    float* mbuf   = (float*)(ws + M_OFF);

    // chunk rows of (N_B*TP floats); leave 512B tail pad (dma4 over-read)
    size_t usable = (ws_size > M_OFF + 4096) ? (ws_size - M_OFF - 512) : 0;
    int CH = (int)(usable / ((size_t)N_B * TP * 4));
    CH &= ~7;
    if (CH > S_LEN) CH = S_LEN;
    if (CH < 8) CH = 8;

    for (int cs = 0; cs < S_LEN; cs += CH) {
        int ch = S_LEN - cs; if (ch > CH) ch = CH;
        int rows = ch * N_B;
        int pre_blocks = (rows + 3) / 4;
        ctc_pre_kernel<<<pre_blocks, 256, 0, stream>>>(inp, lab, mbuf, cs, ch);
        ctc_dp_kernel<<<N_B, 64, 0, stream>>>(mbuf, vst, losses, cs, ch);
    }
    ctc_sum_kernel<<<1, 64, 0, stream>>>(losses, out);
}

// Round 3
// 143.129 us; speedup vs baseline: 2.5111x; 1.8476x over previous
//
#include <hip/hip_runtime.h>
#include <hip/hip_bf16.h>

// CTC forward loss, linear-domain DP with power-of-2 rescaling.
// k1: q[n][s][c] = clip(p)/sum  (128 floats = 512B per row, coalesced)
// k2: serial DP, 1 wave/batch. 5 states/lane. Cross-lane via DPP row_shr1
//     + row_bcast15 (pure VALU). Per-lane int exp2-scale `ref`, rescale
//     every 4 steps via exponent bits + ldexp. No transcendentals in loop.
//     Rows staged 2-at-a-time via global_load_lds dwordx4, 62 pairs deep.
// k3: sum losses -> scalar.

#define S_LEN 1024
#define N_B   32
#define C_CLS 128
#define SKIPV (-5.0f)
#define LOV   (1e-5f)
#define L2E   7.213475f            // 5 * log2(e)
#define E_M5  6.7379470e-03f       // e^-5
#define LN2   0.69314718f

__device__ __forceinline__ void dma16(const float* g, float* l) {
    __builtin_amdgcn_global_load_lds((const __attribute__((address_space(1))) void*)g,
                                     (__attribute__((address_space(3))) void*)l, 16, 0, 0);
}

// lane L receives x from lane L-1 (lane 0 gets garbage; caller overrides)
__device__ __forceinline__ int shl1_i(int x, bool row0lane) {
    int a = __builtin_amdgcn_update_dpp(0, x, 0x111, 0xf, 0xf, false); // row_shr:1
    int b = __builtin_amdgcn_update_dpp(0, x, 0x142, 0xf, 0xf, false); // row_bcast15
    return row0lane ? b : a;
}
__device__ __forceinline__ float shl1_f(float x, bool row0lane) {
    return __builtin_bit_cast(float, shl1_i(__builtin_bit_cast(int, x), row0lane));
}

// ---- kernel 1: normalize rows --------------------------------------------
__global__ void ctc_pre_kernel(const float* __restrict__ inp,
                               float* __restrict__ m,
                               int chunk_start, int ch) {
    const int wid  = threadIdx.x >> 6;
    const int lane = threadIdx.x & 63;
    const int r = blockIdx.x * 4 + wid;
    if (r >= ch * N_B) return;
    const int n  = r & 31;
    const int sl = r >> 5;
    const int s  = chunk_start + sl;

    const float* row = inp + ((size_t)s * N_B + n) * C_CLS;
    float2 x = *(const float2*)(row + 2 * lane);
    float p0 = fmaxf(LOV, x.x);
    float p1 = fmaxf(LOV, x.y);
    float sum = p0 + p1;
    #pragma unroll
    for (int off = 32; off; off >>= 1) sum += __shfl_xor(sum, off);
    float rinv = 1.0f / sum;
    float2 q; q.x = p0 * rinv; q.y = p1 * rinv;
    *(float2*)(m + ((size_t)n * ch + sl) * C_CLS + 2 * lane) = q;
}

// ---- kernel 2: serial DP -------------------------------------------------
__global__ void __launch_bounds__(64)
ctc_dp_kernel(const float* __restrict__ q,
              const int* __restrict__ lab,
              float* __restrict__ vst,      // (N, 64, 6)
              float* __restrict__ losses,
              int chunk_start, int ch, int is_last) {
    __shared__ float ring[128][C_CLS];      // 64 KiB, 128 rows
    const int n = blockIdx.x;
    const int lane = threadIdx.x;
    const bool row0lane = (lane & 15) == 0;
    const bool lane0 = (lane == 0);

    // per-lane constant gather byte-offsets: state t=5*lane+j
    int offs[5];
    #pragma unroll
    for (int j = 0; j < 5; ++j) {
        int t = 5 * lane + j;
        if (t & 1) {
            int c = (t - 1) >> 1; if (c > 127) c = 127;
            offs[j] = lab[c * N_B + n] << 2;
        } else offs[j] = 0;                  // blank = class 0
    }

    float u0, u1, u2, u3, u4; int ref;
    float* vr = vst + ((size_t)n * 64 + lane) * 6;
    if (chunk_start == 0) {
        ref = (int)(-36.067375f * (float)lane);
        u0 = exp2f(fmaf(-L2E, (float)(5 * lane + 0), -(float)ref));
        u1 = exp2f(fmaf(-L2E, (float)(5 * lane + 1), -(float)ref));
        u2 = exp2f(fmaf(-L2E, (float)(5 * lane + 2), -(float)ref));
        u3 = exp2f(fmaf(-L2E, (float)(5 * lane + 3), -(float)ref));
        u4 = exp2f(fmaf(-L2E, (float)(5 * lane + 4), -(float)ref));
    } else {
        u0 = vr[0]; u1 = vr[1]; u2 = vr[2]; u3 = vr[3]; u4 = vr[4];
        ref = __builtin_bit_cast(int, vr[5]);
    }

    const float* qn = q + (size_t)n * ch * C_CLS;
    const int lastp = (ch - 2) >> 1;

    // prologue: 62 pairs in flight
    for (int p = 0; p < 62; ++p) {
        int sp = (p < lastp) ? p : lastp;
        dma16(qn + (size_t)(2 * sp) * C_CLS + 4 * lane, &ring[(2 * p) & 127][0]);
    }
    asm volatile("s_waitcnt vmcnt(61)" ::: "memory");
    __builtin_amdgcn_sched_barrier(0);

    // prefetch row 0 q's
    const char* rp0 = (const char*)&ring[0][0];
    float cq0 = *(const float*)(rp0 + offs[0]);
    float cq1 = *(const float*)(rp0 + offs[1]);
    float cq2 = *(const float*)(rp0 + offs[2]);
    float cq3 = *(const float*)(rp0 + offs[3]);
    float cq4 = *(const float*)(rp0 + offs[4]);

    const int ngroups = ch >> 2;
    for (int g = 0; g < ngroups; ++g) {
        // group-constant cross-lane scale + lane0 skip value
        int refL = shl1_i(ref, row0lane);
        float fct = ldexpf(1.0f, refL - ref);
        float prev0 = exp2f(fmaf(-L2E, (float)(chunk_start + (g << 2)), -(float)ref));
        #pragma unroll
        for (int k = 0; k < 4; ++k) {
            const int i = (g << 2) + k;
            if ((k & 1) == 0) {                 // even step: stage pair i/2+62
                int p = (i >> 1) + 62;
                int sp = (p < lastp) ? p : lastp;
                dma16(qn + (size_t)(2 * sp) * C_CLS + 4 * lane,
                      &ring[(2 * p) & 127][0]);
                asm volatile("s_waitcnt vmcnt(61)" ::: "memory");
                __builtin_amdgcn_sched_barrier(0);
            }
            // prefetch next row's q's
            const char* np = (const char*)&ring[(i + 1) & 127][0];
            float nq0 = *(const float*)(np + offs[0]);
            float nq1 = *(const float*)(np + offs[1]);
            float nq2 = *(const float*)(np + offs[2]);
            float nq3 = *(const float*)(np + offs[3]);
            float nq4 = *(const float*)(np + offs[4]);
            // step
            float u4s  = shl1_f(u4, row0lane);
            float prev = lane0 ? prev0 : u4s * fct;
            float w0 = cq0 * (u0 + prev);
            float w1 = cq1 * (u1 + u0);
            float w2 = cq2 * (u2 + u1);
            float w3 = cq3 * (u3 + u2);
            float w4 = cq4 * (u4 + u3);
            u0 = w0; u1 = w1; u2 = w2; u3 = w3; u4 = w4;
            prev0 *= E_M5;
            cq0 = nq0; cq1 = nq1; cq2 = nq2; cq3 = nq3; cq4 = nq4;
        }
        // rescale: M = f*2^e, f in [0.5,1)
        float M = fmaxf(fmaxf(fmaxf(u0, u1), fmaxf(u2, u3)), u4);
        int e = ((__builtin_bit_cast(int, M) >> 23) & 255) - 126;
        ref += e;
        u0 = ldexpf(u0, -e); u1 = ldexpf(u1, -e); u2 = ldexpf(u2, -e);
        u3 = ldexpf(u3, -e); u4 = ldexpf(u4, -e);
    }

    if (!is_last) {
        vr[0] = u0; vr[1] = u1; vr[2] = u2; vr[3] = u3; vr[4] = u4;
        vr[5] = __builtin_bit_cast(float, ref);
    } else if (lane == 51) {
        // u0 = state 255, u1 = state 256
        losses[n] = -(LN2 * (float)ref + __logf(u0 + u1));
    }
}

// ---- kernel 3: reduce ----------------------------------------------------
__global__ void ctc_sum_kernel(const float* __restrict__ losses,
                               float* __restrict__ out) {
    const int lane = threadIdx.x;
    float x = (lane < N_B) ? losses[lane] : 0.0f;
    #pragma unroll
    for (int off = 32; off; off >>= 1) x += __shfl_xor(x, off);
    if (lane == 0) out[0] = x / (float)N_B;
}

extern "C" void kernel_launch(void* const* d_in, const int* in_sizes, int n_in,
                              void* d_out, int out_size, void* d_ws, size_t ws_size,
                              hipStream_t stream) {
    const float* inp = (const float*)d_in[0];   // (S, N, C) f32
    const int*   lab = (const int*)d_in[1];     // (L, N) int32
    float* out = (float*)d_out;

    char* ws = (char*)d_ws;
    const size_t V_BYTES = (size_t)N_B * 64 * 6 * 4;              // 49152
    const size_t L_OFF = V_BYTES;
    const size_t M_OFF = (L_OFF + N_B * 4 + 511) & ~(size_t)511;  // 49664
    float* vst    = (float*)ws;
    float* losses = (float*)(ws + L_OFF);
    float* mbuf   = (float*)(ws + M_OFF);

    size_t usable = (ws_size > M_OFF) ? (ws_size - M_OFF) : 0;
    int CH = (int)(usable / ((size_t)N_B * C_CLS * 4));
    CH &= ~127;                       // multiple of 128
    if (CH > S_LEN) CH = S_LEN;
    if (CH < 128) CH = 128;

    for (int cs = 0; cs < S_LEN; cs += CH) {
        int ch = S_LEN - cs; if (ch > CH) ch = CH;
        int pre_blocks = ch * N_B / 4;
        ctc_pre_kernel<<<pre_blocks, 256, 0, stream>>>(inp, mbuf, cs, ch);
        ctc_dp_kernel<<<N_B, 64, 0, stream>>>(mbuf, lab, vst, losses,
                                              cs, ch, (cs + ch >= S_LEN) ? 1 : 0);
    }
    ctc_sum_kernel<<<1, 64, 0, stream>>>(losses, out);
}